// Round 4
// baseline (132.979 us; speedup 1.0000x reference)
//
#include <hip/hip_runtime.h>
#include <hip/hip_bf16.h>

#define WDIM 512
#define CHN  512
#define NB   32
#define SZ   64
#define MTOT 4096   // SZ*SZ

typedef __attribute__((ext_vector_type(4))) float f32x4;
typedef __attribute__((ext_vector_type(8))) short short8;
typedef __attribute__((ext_vector_type(4))) int   int4v;
typedef __attribute__((ext_vector_type(4))) float float4v;

// ---------------- setup: per-batch affine+norm, per-(n,c) params ----------------
__global__ __launch_bounds__(512) void setup_kernel(
    const float* __restrict__ w,
    const float* __restrict__ affine_w,
    const float* __restrict__ affine_b,
    const float* __restrict__ freqs,
    const float* __restrict__ phases,
    float* __restrict__ frx_o, float* __restrict__ fry_o,
    float* __restrict__ pha_o, float* __restrict__ amp_o)
{
    const int n = blockIdx.x;
    const int tid = threadIdx.x;
    __shared__ float red[8][4];
    __shared__ float par[4];

    float wv = w[n * WDIM + tid];
    float p0 = wv * affine_w[0 * WDIM + tid];
    float p1 = wv * affine_w[1 * WDIM + tid];
    float p2 = wv * affine_w[2 * WDIM + tid];
    float p3 = wv * affine_w[3 * WDIM + tid];
    #pragma unroll
    for (int off = 32; off >= 1; off >>= 1) {
        p0 += __shfl_down(p0, off);
        p1 += __shfl_down(p1, off);
        p2 += __shfl_down(p2, off);
        p3 += __shfl_down(p3, off);
    }
    const int wave = tid >> 6;
    if ((tid & 63) == 0) {
        red[wave][0] = p0; red[wave][1] = p1;
        red[wave][2] = p2; red[wave][3] = p3;
    }
    __syncthreads();
    if (tid == 0) {
        const float gain = 0.04419417382415922f; // 1/sqrt(512)
        float t[4];
        #pragma unroll
        for (int j = 0; j < 4; ++j) {
            float s = 0.0f;
            #pragma unroll
            for (int v = 0; v < 8; ++v) s += red[v][j];
            t[j] = s * gain + affine_b[j];
        }
        float inv = 1.0f / sqrtf(t[0] * t[0] + t[1] * t[1]);
        float c = t[0] * inv, s = t[1] * inv, tx = t[2] * inv, ty = t[3] * inv;
        par[0] = c;
        par[1] = s;
        par[2] = -c * tx + s * ty;
        par[3] = -s * tx - c * ty;
    }
    __syncthreads();
    const float c_ = par[0], s_ = par[1], tr0 = par[2], tr1 = par[3];
    const int ci = tid; // CH == 512 == blockDim
    float fx = freqs[ci * 2 + 0], fy = freqs[ci * 2 + 1];
    float frx = fx * c_ + fy * s_;
    float fry = -fx * s_ + fy * c_;
    float ph = phases[ci] + fx * tr0 + fy * tr1;
    float r = sqrtf(frx * frx + fry * fry);
    float amp = 1.0f - (r - 2.0f) * (1.0f / 30.0f); // (r-BW)/(SR/2-BW)
    amp = fminf(fmaxf(amp, 0.0f), 1.0f);
    frx_o[n * CHN + ci] = frx;
    fry_o[n * CHN + ci] = fry;
    pha_o[n * CHN + ci] = ph;
    amp_o[n * CHN + ci] = amp;
}

// ---------------- prep: A-tables (sA/cA) + weight->bf16, one launch ----------------
__global__ __launch_bounds__(512) void prep_kernel(
    const float* __restrict__ frx, const float* __restrict__ amp,
    const float* __restrict__ wsrc,
    float* __restrict__ SA, float* __restrict__ CA,
    __hip_bfloat16* __restrict__ wbf)
{
    const int b = blockIdx.x;
    if (b < NB * 64) {
        const int n = b >> 6;
        const int w = b & 63;
        const int c = threadIdx.x;
        float f = frx[n * CHN + c];
        float a = amp[n * CHN + c];
        float xs = (float)(2 * w + 1) * (1.0f / 128.0f) - 0.5f;
        float arg = xs * f; // revolutions: v_sin computes sin(2pi*x)
        size_t idx = ((size_t)(n * 64 + w)) * CHN + c;
        SA[idx] = a * __builtin_amdgcn_sinf(arg);
        CA[idx] = a * __builtin_amdgcn_cosf(arg);
    } else {
        int i = (b - NB * 64) * 512 + threadIdx.x;
        wbf[i] = __float2bfloat16(wsrc[i] * 0.04419417382415922f);
    }
}

// ---------------- fused features + GEMM, software-pipelined ----------------
// 128(m) x 128(k) tile, BK=64, 256 thr (4 waves 2x2), double-buffered As/Bs,
// one barrier per K-step. Per iter: issue next Bs stage + next SA/CA loads,
// run current MFMAs (hides global latency), build next feature tile, barrier.
__global__ __launch_bounds__(256, 2) void fused_kernel(
    const float* __restrict__ fry, const float* __restrict__ pha,
    const float* __restrict__ SA, const float* __restrict__ CA,
    const __hip_bfloat16* __restrict__ wbf,
    float* __restrict__ out)
{
    __shared__ __align__(16) __hip_bfloat16 As[2][128 * 64]; // features, swizzled
    __shared__ __align__(16) __hip_bfloat16 Bs[2][128 * 64]; // weight, swizzled
    __shared__ __align__(16) float sB[2][CHN];
    __shared__ __align__(16) float cB[2][CHN];

    const int tid = threadIdx.x;
    const int mb = blockIdx.x * 128;
    const int kb = blockIdx.y * 128;
    const int n  = blockIdx.z;
    const int h0 = mb >> 6;

    // h-tables: sB/cB for the block's 2 h rows (cooperative, once)
    #pragma unroll
    for (int u = 0; u < 2; ++u) {
        int c = tid + u * 256;
        float fy = fry[n * CHN + c];
        float ph = pha[n * CHN + c];
        #pragma unroll
        for (int hh = 0; hh < 2; ++hh) {
            float ys = (float)(2 * (h0 + hh) + 1) * (1.0f / 128.0f) - 0.5f;
            float bv = ys * fy + ph;
            sB[hh][c] = __builtin_amdgcn_sinf(bv);
            cB[hh][c] = __builtin_amdgcn_cosf(bv);
        }
    }

    const int lane = tid & 63;
    const int wid  = tid >> 6;
    const int ln15 = lane & 15;
    const int hi4  = lane >> 4;
    const int wk = (wid >> 1) * 64;
    const int wm = (wid & 1) * 64;
    const int cc0 = (tid & 7) * 8;
    const int rb  = tid >> 3;

    const float* saL = SA + ((size_t)(n * 64 + rb)) * CHN + cc0;
    const float* saH = saL + 32 * CHN;
    const float* caL = CA + ((size_t)(n * 64 + rb)) * CHN + cc0;
    const float* caH = caL + 32 * CHN;

    // ---- pipeline helpers ----
    auto stageB = [&](int buf, int c0) {
        #pragma unroll
        for (int u = 0; u < 4; ++u) {
            int unit = u * 256 + tid;
            int row = unit >> 3;
            int cbyte = ((unit & 7) << 4) ^ ((row & 7) << 4);
            const __hip_bfloat16* src = wbf + (size_t)(kb + row) * CHN + c0 + (cbyte >> 1);
            char* ldsbase = (char*)Bs[buf] + (u * 256 + (wid << 6)) * 16; // wave-uniform
            __builtin_amdgcn_global_load_lds(
                (const __attribute__((address_space(1))) unsigned int*)src,
                (__attribute__((address_space(3))) unsigned int*)ldsbase, 16, 0, 0);
        }
    };

    float4v Ps0, Ps1, Ps2, Ps3, Pc0, Pc1, Pc2, Pc3;
    auto loadP = [&](int c0) {
        Ps0 = *(const float4v*)(saL + c0); Ps1 = *(const float4v*)(saL + c0 + 4);
        Ps2 = *(const float4v*)(saH + c0); Ps3 = *(const float4v*)(saH + c0 + 4);
        Pc0 = *(const float4v*)(caL + c0); Pc1 = *(const float4v*)(caL + c0 + 4);
        Pc2 = *(const float4v*)(caH + c0); Pc3 = *(const float4v*)(caH + c0 + 4);
    };

    auto features = [&](int buf, int c0) {
        #pragma unroll
        for (int i = 0; i < 4; ++i) {
            int m = rb + i * 32;
            int hh = i >> 1;
            float4v A0 = (i & 1) ? Ps2 : Ps0, A1 = (i & 1) ? Ps3 : Ps1;
            float4v C0 = (i & 1) ? Pc2 : Pc0, C1 = (i & 1) ? Pc3 : Pc1;
            float4v B0 = *(const float4v*)&sB[hh][c0 + cc0];
            float4v B1 = *(const float4v*)&sB[hh][c0 + cc0 + 4];
            float4v D0 = *(const float4v*)&cB[hh][c0 + cc0];
            float4v D1 = *(const float4v*)&cB[hh][c0 + cc0 + 4];
            union { __hip_bfloat16 h[8]; int4v v; } t;
            #pragma unroll
            for (int j = 0; j < 4; ++j)
                t.h[j] = __float2bfloat16(A0[j] * D0[j] + C0[j] * B0[j]);
            #pragma unroll
            for (int j = 0; j < 4; ++j)
                t.h[4 + j] = __float2bfloat16(A1[j] * D1[j] + C1[j] * B1[j]);
            *(int4v*)((char*)As[buf] + m * 128 + ((cc0 * 2) ^ ((m & 7) << 4))) = t.v;
        }
    };

    f32x4 acc[4][4];
    #pragma unroll
    for (int a = 0; a < 4; ++a)
        #pragma unroll
        for (int b = 0; b < 4; ++b)
            acc[a][b] = (f32x4)0.0f;

    auto mfmaStep = [&](int buf) {
        #pragma unroll
        for (int kk = 0; kk < 2; ++kk) {
            short8 wf[4], ff[4];
            #pragma unroll
            for (int ki = 0; ki < 4; ++ki) {
                int row = wk + ki * 16 + ln15;
                wf[ki] = *(const short8*)((char*)Bs[buf] + row * 128 +
                          (((kk * 32 + hi4 * 8) * 2) ^ ((row & 7) << 4)));
            }
            #pragma unroll
            for (int mj = 0; mj < 4; ++mj) {
                int m = wm + mj * 16 + ln15;
                ff[mj] = *(const short8*)((char*)As[buf] + m * 128 +
                          (((kk * 32 + hi4 * 8) * 2) ^ ((m & 7) << 4)));
            }
            #pragma unroll
            for (int ki = 0; ki < 4; ++ki)
                #pragma unroll
                for (int mj = 0; mj < 4; ++mj)
                    acc[ki][mj] = __builtin_amdgcn_mfma_f32_16x16x32_bf16(
                        wf[ki], ff[mj], acc[ki][mj], 0, 0, 0);
        }
    };

    // ---- prologue ----
    stageB(0, 0);
    loadP(0);
    __syncthreads();          // sB/cB visible
    features(0, 0);
    __syncthreads();          // As[0] visible, Bs[0] drained

    // ---- main loop: 1 barrier per K-step ----
    #pragma unroll 1
    for (int kc = 0; kc < 8; ++kc) {
        const int cur = kc & 1;
        if (kc < 7) {
            stageB(cur ^ 1, (kc + 1) * 64);   // issue early
            loadP((kc + 1) * 64);             // issue early
        }
        mfmaStep(cur);                        // hides global latency
        if (kc < 7) {
            features(cur ^ 1, (kc + 1) * 64); // consume late
            __syncthreads();
        }
    }

    // ---- epilogue: out[n][k][hw], D col (ln15) = m -> coalesced ----
    #pragma unroll
    for (int ki = 0; ki < 4; ++ki) {
        #pragma unroll
        for (int mj = 0; mj < 4; ++mj) {
            int kg = kb + wk + ki * 16 + hi4 * 4;
            int mg = mb + wm + mj * 16 + ln15;
            float* op = out + ((size_t)n * CHN + kg) * MTOT + mg;
            #pragma unroll
            for (int r = 0; r < 4; ++r)
                op[(size_t)r * MTOT] = acc[ki][mj][r];
        }
    }
}

extern "C" void kernel_launch(void* const* d_in, const int* in_sizes, int n_in,
                              void* d_out, int out_size, void* d_ws, size_t ws_size,
                              hipStream_t stream) {
    const float* w        = (const float*)d_in[0];
    const float* affine_w = (const float*)d_in[1];
    const float* affine_b = (const float*)d_in[2];
    const float* weight   = (const float*)d_in[3];
    const float* freqs    = (const float*)d_in[4];
    const float* phases   = (const float*)d_in[5];
    float* out = (float*)d_out;

    char* ws = (char*)d_ws;
    float* frx = (float*)(ws + 0);
    float* fry = (float*)(ws + 65536);
    float* pha = (float*)(ws + 131072);
    float* amp = (float*)(ws + 196608);
    __hip_bfloat16* wbf = (__hip_bfloat16*)(ws + 262144);   // 512 KB
    float* SA = (float*)(ws + 786432);                       // 4 MB
    float* CA = (float*)(ws + 786432 + 4194304);             // 4 MB

    setup_kernel<<<NB, 512, 0, stream>>>(w, affine_w, affine_b, freqs, phases,
                                         frx, fry, pha, amp);
    prep_kernel<<<NB * 64 + (CHN * CHN) / 512, 512, 0, stream>>>(
        frx, amp, weight, SA, CA, wbf);

    dim3 grid(MTOT / 128, CHN / 128, NB);
    fused_kernel<<<grid, 256, 0, stream>>>(fry, pha, SA, CA, wbf, out);
}

// Round 5
// 112.674 us; speedup vs baseline: 1.1802x; 1.1802x over previous
//
#include <hip/hip_runtime.h>
#include <hip/hip_bf16.h>

#define WDIM 512
#define CHN  512
#define NB   32
#define SZ   64
#define MTOT 4096   // SZ*SZ

typedef __attribute__((ext_vector_type(4))) float f32x4;
typedef __attribute__((ext_vector_type(8))) short short8;
typedef __attribute__((ext_vector_type(4))) int   int4v;
typedef __attribute__((ext_vector_type(4))) float float4v;

// ---------------- setup: per-batch affine+norm, per-(n,c) params ----------------
__global__ __launch_bounds__(512) void setup_kernel(
    const float* __restrict__ w,
    const float* __restrict__ affine_w,
    const float* __restrict__ affine_b,
    const float* __restrict__ freqs,
    const float* __restrict__ phases,
    float* __restrict__ frx_o, float* __restrict__ fry_o,
    float* __restrict__ pha_o, float* __restrict__ amp_o)
{
    const int n = blockIdx.x;
    const int tid = threadIdx.x;
    __shared__ float red[8][4];
    __shared__ float par[4];

    float wv = w[n * WDIM + tid];
    float p0 = wv * affine_w[0 * WDIM + tid];
    float p1 = wv * affine_w[1 * WDIM + tid];
    float p2 = wv * affine_w[2 * WDIM + tid];
    float p3 = wv * affine_w[3 * WDIM + tid];
    #pragma unroll
    for (int off = 32; off >= 1; off >>= 1) {
        p0 += __shfl_down(p0, off);
        p1 += __shfl_down(p1, off);
        p2 += __shfl_down(p2, off);
        p3 += __shfl_down(p3, off);
    }
    const int wave = tid >> 6;
    if ((tid & 63) == 0) {
        red[wave][0] = p0; red[wave][1] = p1;
        red[wave][2] = p2; red[wave][3] = p3;
    }
    __syncthreads();
    if (tid == 0) {
        const float gain = 0.04419417382415922f; // 1/sqrt(512)
        float t[4];
        #pragma unroll
        for (int j = 0; j < 4; ++j) {
            float s = 0.0f;
            #pragma unroll
            for (int v = 0; v < 8; ++v) s += red[v][j];
            t[j] = s * gain + affine_b[j];
        }
        float inv = 1.0f / sqrtf(t[0] * t[0] + t[1] * t[1]);
        float c = t[0] * inv, s = t[1] * inv, tx = t[2] * inv, ty = t[3] * inv;
        par[0] = c;
        par[1] = s;
        par[2] = -c * tx + s * ty;
        par[3] = -s * tx - c * ty;
    }
    __syncthreads();
    const float c_ = par[0], s_ = par[1], tr0 = par[2], tr1 = par[3];
    const int ci = tid; // CH == 512 == blockDim
    float fx = freqs[ci * 2 + 0], fy = freqs[ci * 2 + 1];
    float frx = fx * c_ + fy * s_;
    float fry = -fx * s_ + fy * c_;
    float ph = phases[ci] + fx * tr0 + fy * tr1;
    float r = sqrtf(frx * frx + fry * fry);
    float amp = 1.0f - (r - 2.0f) * (1.0f / 30.0f); // (r-BW)/(SR/2-BW)
    amp = fminf(fmaxf(amp, 0.0f), 1.0f);
    frx_o[n * CHN + ci] = frx;
    fry_o[n * CHN + ci] = fry;
    pha_o[n * CHN + ci] = ph;
    amp_o[n * CHN + ci] = amp;
}

// ---------------- prep: A-tables (sA/cA) + weight->bf16, one launch ----------------
__global__ __launch_bounds__(512) void prep_kernel(
    const float* __restrict__ frx, const float* __restrict__ amp,
    const float* __restrict__ wsrc,
    float* __restrict__ SA, float* __restrict__ CA,
    __hip_bfloat16* __restrict__ wbf)
{
    const int b = blockIdx.x;
    if (b < NB * 64) {
        const int n = b >> 6;
        const int w = b & 63;
        const int c = threadIdx.x;
        float f = frx[n * CHN + c];
        float a = amp[n * CHN + c];
        float xs = (float)(2 * w + 1) * (1.0f / 128.0f) - 0.5f;
        float arg = xs * f; // revolutions: v_sin computes sin(2pi*x)
        size_t idx = ((size_t)(n * 64 + w)) * CHN + c;
        SA[idx] = a * __builtin_amdgcn_sinf(arg);
        CA[idx] = a * __builtin_amdgcn_cosf(arg);
    } else {
        int i = (b - NB * 64) * 512 + threadIdx.x;
        wbf[i] = __float2bfloat16(wsrc[i] * 0.04419417382415922f);
    }
}

// ---------------- fused features + GEMM ----------------
// 128(m) x 256(k) block tile, BK=64, 256 thr = 4 waves arranged 1(m) x 4(k):
// wave tile 128 m x 64 k (acc 4x8). Single-buffered swizzled As/Bs, 2 barriers/K-step.
// Frag-read bytes per output cell: 128*(1/128 + 1/64) = 3 (was 4 at 64x64).
__global__ __launch_bounds__(256, 2) void fused_kernel(
    const float* __restrict__ fry, const float* __restrict__ pha,
    const float* __restrict__ SA, const float* __restrict__ CA,
    const __hip_bfloat16* __restrict__ wbf,
    float* __restrict__ out)
{
    __shared__ __align__(16) __hip_bfloat16 As[128 * 64]; // features [m][c] swizzled (16 KB)
    __shared__ __align__(16) __hip_bfloat16 Bs[256 * 64]; // weight   [k][c] swizzled (32 KB)
    __shared__ __align__(16) float sB[2][CHN];
    __shared__ __align__(16) float cB[2][CHN];

    const int tid = threadIdx.x;
    const int mb = blockIdx.x * 128;
    const int kb = blockIdx.y * 256;
    const int n  = blockIdx.z;
    const int h0 = mb >> 6;

    // per-block h-tables: sB/cB for the block's 2 h rows
    #pragma unroll
    for (int u = 0; u < 2; ++u) {
        int c = tid + u * 256;
        float fy = fry[n * CHN + c];
        float ph = pha[n * CHN + c];
        #pragma unroll
        for (int hh = 0; hh < 2; ++hh) {
            float ys = (float)(2 * (h0 + hh) + 1) * (1.0f / 128.0f) - 0.5f;
            float bv = ys * fy + ph;
            sB[hh][c] = __builtin_amdgcn_sinf(bv);
            cB[hh][c] = __builtin_amdgcn_cosf(bv);
        }
    }

    const int lane = tid & 63;
    const int wid  = tid >> 6;        // 0..3
    const int ln15 = lane & 15;
    const int hi4  = lane >> 4;
    const int wk   = wid * 64;        // k offset of wave within block k-tile

    const int cc0 = (tid & 7) * 8;  // c-subchunk within 64
    const int rb  = tid >> 3;       // 0..31

    // A-table row pointers (w = rb and rb+32)
    const float* saL = SA + ((size_t)(n * 64 + rb)) * CHN + cc0;
    const float* saH = saL + 32 * CHN;
    const float* caL = CA + ((size_t)(n * 64 + rb)) * CHN + cc0;
    const float* caH = caL + 32 * CHN;

    f32x4 acc[4][8];
    #pragma unroll
    for (int a = 0; a < 4; ++a)
        #pragma unroll
        for (int b = 0; b < 8; ++b)
            acc[a][b] = (f32x4)0.0f;

    #pragma unroll 1
    for (int kc = 0; kc < 8; ++kc) {
        const int c0 = kc * 64;
        __syncthreads(); // prev MFMA frag reads done (also covers sB/cB on kc==0)

        // stage Bs[256][64]: linear LDS dest, pre-swizzled global source (8 units/thread)
        #pragma unroll
        for (int u = 0; u < 8; ++u) {
            int unit = u * 256 + tid;
            int row = unit >> 3;
            int cbyte = ((unit & 7) << 4) ^ ((row & 7) << 4);
            const __hip_bfloat16* src = wbf + (size_t)(kb + row) * CHN + c0 + (cbyte >> 1);
            char* ldsbase = (char*)Bs + (u * 256 + (wid << 6)) * 16; // wave-uniform
            __builtin_amdgcn_global_load_lds(
                (const __attribute__((address_space(1))) unsigned int*)src,
                (__attribute__((address_space(3))) unsigned int*)ldsbase, 16, 0, 0);
        }

        // features via sA*cB + cA*sB
        float4v s0 = *(const float4v*)(saL + c0), s1 = *(const float4v*)(saL + c0 + 4);
        float4v s2 = *(const float4v*)(saH + c0), s3 = *(const float4v*)(saH + c0 + 4);
        float4v q0 = *(const float4v*)(caL + c0), q1 = *(const float4v*)(caL + c0 + 4);
        float4v q2 = *(const float4v*)(caH + c0), q3 = *(const float4v*)(caH + c0 + 4);
        #pragma unroll
        for (int i = 0; i < 4; ++i) {
            int m = rb + i * 32;
            int hh = i >> 1;
            float4v A0 = (i & 1) ? s2 : s0, A1 = (i & 1) ? s3 : s1;
            float4v C0 = (i & 1) ? q2 : q0, C1 = (i & 1) ? q3 : q1;
            float4v B0 = *(const float4v*)&sB[hh][c0 + cc0];
            float4v B1 = *(const float4v*)&sB[hh][c0 + cc0 + 4];
            float4v D0 = *(const float4v*)&cB[hh][c0 + cc0];
            float4v D1 = *(const float4v*)&cB[hh][c0 + cc0 + 4];
            union { __hip_bfloat16 h[8]; int4v v; } t;
            #pragma unroll
            for (int j = 0; j < 4; ++j)
                t.h[j] = __float2bfloat16(A0[j] * D0[j] + C0[j] * B0[j]);
            #pragma unroll
            for (int j = 0; j < 4; ++j)
                t.h[4 + j] = __float2bfloat16(A1[j] * D1[j] + C1[j] * B1[j]);
            *(int4v*)((char*)As + m * 128 + ((cc0 * 2) ^ ((m & 7) << 4))) = t.v;
        }
        __syncthreads(); // As visible + vmcnt drained (Bs complete)

        // MFMA: 64 MFMA per wave-kc from 24 ds_read_b128
        #pragma unroll
        for (int kk = 0; kk < 2; ++kk) {
            short8 wf[4], ff[8];
            #pragma unroll
            for (int ki = 0; ki < 4; ++ki) {
                int row = wk + ki * 16 + ln15;
                wf[ki] = *(const short8*)((char*)Bs + row * 128 +
                          (((kk * 32 + hi4 * 8) * 2) ^ ((row & 7) << 4)));
            }
            #pragma unroll
            for (int mj = 0; mj < 8; ++mj) {
                int m = mj * 16 + ln15;
                ff[mj] = *(const short8*)((char*)As + m * 128 +
                          (((kk * 32 + hi4 * 8) * 2) ^ ((m & 7) << 4)));
            }
            #pragma unroll
            for (int ki = 0; ki < 4; ++ki)
                #pragma unroll
                for (int mj = 0; mj < 8; ++mj)
                    acc[ki][mj] = __builtin_amdgcn_mfma_f32_16x16x32_bf16(
                        wf[ki], ff[mj], acc[ki][mj], 0, 0, 0);
        }
    }

    // epilogue: out[n][k][hw], D col (ln15) = m -> coalesced
    #pragma unroll
    for (int ki = 0; ki < 4; ++ki) {
        #pragma unroll
        for (int mj = 0; mj < 8; ++mj) {
            int kg = kb + wk + ki * 16 + hi4 * 4;
            int mg = mb + mj * 16 + ln15;
            float* op = out + ((size_t)n * CHN + kg) * MTOT + mg;
            #pragma unroll
            for (int r = 0; r < 4; ++r)
                op[(size_t)r * MTOT] = acc[ki][mj][r];
        }
    }
}

extern "C" void kernel_launch(void* const* d_in, const int* in_sizes, int n_in,
                              void* d_out, int out_size, void* d_ws, size_t ws_size,
                              hipStream_t stream) {
    const float* w        = (const float*)d_in[0];
    const float* affine_w = (const float*)d_in[1];
    const float* affine_b = (const float*)d_in[2];
    const float* weight   = (const float*)d_in[3];
    const float* freqs    = (const float*)d_in[4];
    const float* phases   = (const float*)d_in[5];
    float* out = (float*)d_out;

    char* ws = (char*)d_ws;
    float* frx = (float*)(ws + 0);
    float* fry = (float*)(ws + 65536);
    float* pha = (float*)(ws + 131072);
    float* amp = (float*)(ws + 196608);
    __hip_bfloat16* wbf = (__hip_bfloat16*)(ws + 262144);   // 512 KB
    float* SA = (float*)(ws + 786432);                       // 4 MB
    float* CA = (float*)(ws + 786432 + 4194304);             // 4 MB

    setup_kernel<<<NB, 512, 0, stream>>>(w, affine_w, affine_b, freqs, phases,
                                         frx, fry, pha, amp);
    prep_kernel<<<NB * 64 + (CHN * CHN) / 512, 512, 0, stream>>>(
        frx, amp, weight, SA, CA, wbf);

    dim3 grid(MTOT / 128, CHN / 256, NB);
    fused_kernel<<<grid, 256, 0, stream>>>(fry, pha, SA, CA, wbf, out);
}